// Round 6
// baseline (199.287 us; speedup 1.0000x reference)
//
#include <hip/hip_runtime.h>

// WaveNet gated residual block, MI355X bf16-MFMA implementation (v6).
// v6: persistent-weight multi-tile blocks. 8-wave (512-thr) blocks, grid=256
// (~1/CU); each block processes 8 t-tiles of 64. k1 weights (30 frags = 120
// VGPR/wave) loaded ONCE per block and held in registers across the tile loop
// -- the compiler cannot sink loop-invariant loads, so the v4/v5 per-tile
// weight-load latency serialization is structurally eliminated. Stage tiles
// double-buffered in LDS (reg-staged: issue loads at iter top, ds_write after
// mid barrier -> HBM latency hides under k1 MFMA). z stays in LDS.

#define NB 8
#define NT 16000
#define CIN 128
#define CCOND 80
#define CCP 96
#define TT 64
#define TPC 8        // t-tiles per block
#define NCHUNK 32    // ceil(250 / TPC)

typedef __attribute__((ext_vector_type(8))) __bf16 bf16x8;
typedef __attribute__((ext_vector_type(4))) float f32x4;
typedef __attribute__((ext_vector_type(4))) unsigned short u16x4;
typedef __attribute__((ext_vector_type(4))) unsigned int u32x4;

__device__ __forceinline__ unsigned short f2bf(float f) {
  unsigned int u = __float_as_uint(f);
  return (unsigned short)((u + 0x7fffu + ((u >> 16) & 1u)) >> 16);  // RNE
}
__device__ __forceinline__ bf16x8 ldb8(const unsigned short* p) {
  return *reinterpret_cast<const bf16x8*>(p);
}

// ---- pack weights to bf16 [M][K] ----
__global__ void pack_weights(const float* __restrict__ wc, const float* __restrict__ wcd,
                             const float* __restrict__ wo, const float* __restrict__ wsk,
                             unsigned short* __restrict__ wpc,   // [256][384] k=tap*128+c
                             unsigned short* __restrict__ wpcd,  // [256][96]  zero-pad k>=80
                             unsigned short* __restrict__ wp2)   // [384][128] rows 0-127 Wout, 128-383 Wskip
{
  int idx = blockIdx.x * 256 + threadIdx.x;
  if (idx < 98304) {
    int o = idx / 384, k = idx - o * 384;
    int tap = k >> 7, c = k & 127;
    wpc[idx] = f2bf(wc[(o * 128 + c) * 3 + tap]);
  } else if (idx < 122880) {
    int i = idx - 98304;
    int o = i / 96, k = i - o * 96;
    wpcd[i] = f2bf(k < CCOND ? wcd[o * CCOND + k] : 0.f);
  } else if (idx < 172032) {
    int i = idx - 122880;
    int m = i >> 7, k = i & 127;
    wp2[i] = f2bf(m < 128 ? wo[m * 128 + k] : wsk[(m - 128) * 128 + k]);
  }
}

// ---- input f32 [B][128][NT] -> bf16 [B][NT][128], paired-u32 stores ----
__global__ void transpose_in64(const float* __restrict__ in, unsigned short* __restrict__ outT)
{
  __shared__ float tile[64][33];
  int t0 = blockIdx.x * 32, c0 = blockIdx.y * 64, b = blockIdx.z;
  int tx = threadIdx.x & 31, ty = threadIdx.x >> 5;  // ty 0..7
  #pragma unroll
  for (int i = 0; i < 8; ++i) {
    int c = c0 + i * 8 + ty;
    tile[i * 8 + ty][tx] = in[((size_t)b * CIN + c) * NT + t0 + tx];
  }
  __syncthreads();
  #pragma unroll
  for (int i = 0; i < 4; ++i) {
    int t = i * 8 + ty;
    unsigned int pk = (unsigned int)f2bf(tile[2 * tx][t]) |
                      ((unsigned int)f2bf(tile[2 * tx + 1][t]) << 16);
    *reinterpret_cast<unsigned int*>(&outT[((size_t)b * NT + t0 + t) * CIN + c0 + 2 * tx]) = pk;
  }
}

// ---- cond f32 [B][80][NT] -> bf16 [B][NT][96] (zero-pad), paired-u32 stores ----
__global__ void transpose_cd(const float* __restrict__ in, unsigned short* __restrict__ outT)
{
  __shared__ float tile[96][33];
  int t0 = blockIdx.x * 32, b = blockIdx.y;
  int tid = threadIdx.x;
  #pragma unroll
  for (int i = 0; i < 12; ++i) {
    int j = i * 256 + tid;
    int c = j >> 5, t = j & 31;
    float v = 0.f;
    if (c < CCOND) v = in[((size_t)b * CCOND + c) * NT + t0 + t];
    tile[c][t] = v;
  }
  __syncthreads();
  #pragma unroll
  for (int i = 0; i < 6; ++i) {
    int j = i * 256 + tid;
    int t = j / 48, cp = j - t * 48;
    unsigned int pk = (unsigned int)f2bf(tile[2 * cp][t]) |
                      ((unsigned int)f2bf(tile[2 * cp + 1][t]) << 16);
    *reinterpret_cast<unsigned int*>(&outT[((size_t)b * NT + t0 + t) * CCP + 2 * cp]) = pk;
  }
}

// ======================= FUSED k1+k2 (v6, persistent weights) =======================
__global__ __launch_bounds__(512, 2) void k12_fused(
    const unsigned short* __restrict__ wpc, const unsigned short* __restrict__ wpcd,
    const unsigned short* __restrict__ wp2, const unsigned short* __restrict__ zp,
    const unsigned short* __restrict__ inT, const unsigned short* __restrict__ cdT,
    const float* __restrict__ bconv, const float* __restrict__ bout,
    const float* __restrict__ bskip, float* __restrict__ out)
{
  // LDS: double-buffered stage tiles + z tile
  __shared__ u32x4 ldsX0_[1152], ldsX1_[1152];  // 72 rows x 256B each (swizzled)
  __shared__ u32x4 ldsC0_[768],  ldsC1_[768];   // 64 rows x 192B each (swizzled)
  __shared__ u32x4 ldsZ_[1024];                 // 64 rows x 256B (swizzled)
  char* ldsZ = (char*)ldsZ_;

  int b = blockIdx.y;
  int tbase = blockIdx.x * TPC;
  int ntiles = 250 - tbase; if (ntiles > TPC) ntiles = TPC;
  int tid = threadIdx.x;
  int lane = tid & 63, w = tid >> 6;            // w 0..7
  int l15 = lane & 15, g = lane >> 4;

  // ---- persistent k1 weights: wave w owns rows {16w..16w+15} and {128+16w..} ----
  bf16x8 wk1t[15], wk1s[15];
  {
    int rt = 16 * w + l15, rs = 128 + 16 * w + l15;
    #pragma unroll
    for (int s = 0; s < 12; ++s) {
      int tap = s >> 2, kc = s & 3;
      wk1t[s] = ldb8(&wpc[(size_t)rt * 384 + tap * 128 + kc * 32 + g * 8]);
      wk1s[s] = ldb8(&wpc[(size_t)rs * 384 + tap * 128 + kc * 32 + g * 8]);
    }
    #pragma unroll
    for (int s = 0; s < 3; ++s) {
      wk1t[12 + s] = ldb8(&wpcd[(size_t)rt * CCP + s * 32 + g * 8]);
      wk1s[12 + s] = ldb8(&wpcd[(size_t)rs * CCP + s * 32 + g * 8]);
    }
  }
  float bt[4], bs[4];
  #pragma unroll
  for (int j = 0; j < 4; ++j) {
    bt[j] = bconv[16 * w + g * 4 + j];
    bs[j] = bconv[128 + 16 * w + g * 4 + j];
  }

  float* skipp = out + (size_t)NB * 128 * NT;

  // staged-tile registers (in flight between issue and ds_write)
  u32x4 sx[3], sc[2];

  // issue global loads for tile `tile` (pre-swizzled source, linear regs)
  auto stage_issue = [&](int tile) {
    int t0 = (tbase + tile) * TT;
    #pragma unroll
    for (int ii = 0; ii < 3; ++ii) {
      int i = w + ii * 8;
      if (i < 18) {
        int row = i * 4 + (lane >> 4);
        int slot = lane & 15;
        int sg = slot ^ (row & 7);
        int t = t0 - 8 + row;
        const unsigned short* src = (t >= 0)
            ? &inT[((size_t)b * NT + t) * CIN + sg * 8] : zp;
        sx[ii] = *reinterpret_cast<const u32x4*>(src);
      }
    }
    #pragma unroll
    for (int ii = 0; ii < 2; ++ii) {
      int i = w + ii * 8;
      if (i < 12) {
        int gi = i * 64 + lane;
        int row = gi / 12, slot = gi - row * 12;
        int sg = slot ^ (row & 3);
        sc[ii] = *reinterpret_cast<const u32x4*>(&cdT[((size_t)b * NT + t0 + row) * CCP + sg * 8]);
      }
    }
  };
  auto stage_write = [&](u32x4* bX, u32x4* bC) {
    #pragma unroll
    for (int ii = 0; ii < 3; ++ii) {
      int i = w + ii * 8;
      if (i < 18) bX[i * 64 + lane] = sx[ii];
    }
    #pragma unroll
    for (int ii = 0; ii < 2; ++ii) {
      int i = w + ii * 8;
      if (i < 12) bC[i * 64 + lane] = sc[ii];
    }
  };

  // prologue: stage tile 0
  stage_issue(0);
  stage_write(ldsX0_, ldsC0_);
  __syncthreads();

  for (int tile = 0; tile < ntiles; ++tile) {
    char* bX  = (char*)((tile & 1) ? ldsX1_ : ldsX0_);
    char* bC  = (char*)((tile & 1) ? ldsC1_ : ldsC0_);
    u32x4* bXn = (tile & 1) ? ldsX0_ : ldsX1_;
    u32x4* bCn = (tile & 1) ? ldsC0_ : ldsC1_;

    if (tile + 1 < ntiles) stage_issue(tile + 1);

    // ---- k1: 15 K-steps from resident weights + LDS B-frags ----
    f32x4 at[4] = {}, as_[4] = {};
    #pragma unroll
    for (int s = 0; s < 15; ++s) {
      bf16x8 bfr[4];
      if (s < 12) {
        int tap = s >> 2, kc = s & 3;
        int ck = kc * 4 + g;
        #pragma unroll
        for (int nf = 0; nf < 4; ++nf) {
          int tl = nf * 16 + l15 + tap * 4;
          bfr[nf] = *reinterpret_cast<const bf16x8*>(&bX[tl * 256 + ((ck ^ (tl & 7)) << 4)]);
        }
      } else {
        int kc = s - 12;
        int ck = kc * 4 + g;
        #pragma unroll
        for (int nf = 0; nf < 4; ++nf) {
          int r = nf * 16 + l15;
          bfr[nf] = *reinterpret_cast<const bf16x8*>(&bC[r * 192 + ((ck ^ (r & 3)) << 4)]);
        }
      }
      #pragma unroll
      for (int nf = 0; nf < 4; ++nf) {
        at[nf]  = __builtin_amdgcn_mfma_f32_16x16x32_bf16(wk1t[s], bfr[nf], at[nf], 0, 0, 0);
        as_[nf] = __builtin_amdgcn_mfma_f32_16x16x32_bf16(wk1s[s], bfr[nf], as_[nf], 0, 0, 0);
      }
    }

    // ---- k2 weights for this tile (L2-hot; latency hides under gate) ----
    bf16x8 wk2[3][4];
    #pragma unroll
    for (int mf = 0; mf < 3; ++mf)
      #pragma unroll
      for (int kc = 0; kc < 4; ++kc)
        wk2[mf][kc] = ldb8(&wp2[(size_t)(48 * w + 16 * mf + l15) * 128 + kc * 32 + g * 8]);

    // ---- gate in-register -> z into swizzled ldsZ ----
    {
      int cg = 2 * w + (g >> 1);
      int off = (g & 1) * 8;
      #pragma unroll
      for (int nf = 0; nf < 4; ++nf) {
        int tl = nf * 16 + l15;
        u16x4 pk;
        #pragma unroll
        for (int j = 0; j < 4; ++j) {
          float a = at[nf][j] + bt[j];
          float s = as_[nf][j] + bs[j];
          float z = (1.f - 2.f / (1.f + __expf(2.f * a))) * (1.f / (1.f + __expf(-s)));
          pk[j] = f2bf(z);
        }
        *reinterpret_cast<u16x4*>(&ldsZ[tl * 256 + ((cg ^ (tl & 7)) << 4) + off]) = pk;
      }
    }
    __syncthreads();   // z visible; stage loads drained (covered by k1)

    // write next tile's stage into the other buffer
    if (tile + 1 < ntiles) stage_write(bXn, bCn);

    // ---- k2: [out;skip] rows 48w..48w+47 ----
    f32x4 acc2[3][4] = {};
    #pragma unroll
    for (int kc = 0; kc < 4; ++kc) {
      bf16x8 bfr[4];
      #pragma unroll
      for (int nf = 0; nf < 4; ++nf) {
        int r = nf * 16 + l15;
        bfr[nf] = *reinterpret_cast<const bf16x8*>(&ldsZ[r * 256 + (((kc * 4 + g) ^ (r & 7)) << 4)]);
      }
      #pragma unroll
      for (int mf = 0; mf < 3; ++mf)
        #pragma unroll
        for (int nf = 0; nf < 4; ++nf)
          acc2[mf][nf] = __builtin_amdgcn_mfma_f32_16x16x32_bf16(wk2[mf][kc], bfr[nf], acc2[mf][nf], 0, 0, 0);
    }

    int t0 = (tbase + tile) * TT;
    #pragma unroll
    for (int mf = 0; mf < 3; ++mf) {
      int mrow = 48 * w + 16 * mf + g * 4;
      #pragma unroll
      for (int j = 0; j < 4; ++j) {
        int m = mrow + j;
        float bv;
        float* basep;
        if (m < 128) { bv = bout[m];        basep = out   + ((size_t)b * 128 + m) * NT; }
        else         { bv = bskip[m - 128]; basep = skipp + ((size_t)b * 256 + (m - 128)) * NT; }
        #pragma unroll
        for (int nf = 0; nf < 4; ++nf)
          basep[t0 + nf * 16 + l15] = acc2[mf][nf][j] + bv;
      }
    }
    __syncthreads();   // protect z + stage buffers before next iteration
  }
}

extern "C" void kernel_launch(void* const* d_in, const int* in_sizes, int n_in,
                              void* d_out, int out_size, void* d_ws, size_t ws_size,
                              hipStream_t stream)
{
  const float* input = (const float*)d_in[0];
  const float* cond  = (const float*)d_in[1];
  const float* wconv = (const float*)d_in[2];
  const float* bconv = (const float*)d_in[3];
  const float* wcond = (const float*)d_in[4];
  const float* wout  = (const float*)d_in[5];
  const float* boutp = (const float*)d_in[6];
  const float* wskip = (const float*)d_in[7];
  const float* bskip = (const float*)d_in[8];
  float* out = (float*)d_out;

  unsigned short* wpc  = (unsigned short*)d_ws;     //  98304
  unsigned short* wpcd = wpc + 98304;               //  24576 (elems 80..95 of each row are zero)
  unsigned short* wp2  = wpcd + 24576;              //  49152
  unsigned short* inT  = wp2 + 49152;               //  16,384,000 elems
  unsigned short* cdT  = inT + (size_t)16384000;    //  12,288,000 elems
  const unsigned short* zp = wpcd + 80;             //  16B of guaranteed zeros (pad region)

  pack_weights<<<672, 256, 0, stream>>>(wconv, wcond, wout, wskip, wpc, wpcd, wp2);
  transpose_in64<<<dim3(500, 2, NB), 256, 0, stream>>>(input, inT);
  transpose_cd<<<dim3(500, NB), 256, 0, stream>>>(cond, cdT);
  k12_fused<<<dim3(NCHUNK, NB), 512, 0, stream>>>(wpc, wpcd, wp2, zp, inT, cdT,
                                                  bconv, boutp, bskip, out);
}

// Round 7
// 150.258 us; speedup vs baseline: 1.3263x; 1.3263x over previous
//
#include <hip/hip_runtime.h>

// WaveNet gated residual block, MI355X bf16-MFMA implementation (v7).
// v7: 8-wave (512-thr) single-tile blocks. Wave owns 16 tanh + 16 sigmoid k1
// rows (2 weight frags/K-step, batched in groups of 5 steps -> 3 L2 round
// trips instead of 15 serial) and 48 k2 rows. No multi-tile persistence
// (v6's spill disaster: VGPR demand ~230 vs cap 128 -> 220MB scratch traffic).
// Register peak kept < 128 (occupancy cliff). LDS 46KB -> 2 blocks/CU.

#define NB 8
#define NT 16000
#define CIN 128
#define CCOND 80
#define CCP 96
#define TT 64

typedef __attribute__((ext_vector_type(8))) __bf16 bf16x8;
typedef __attribute__((ext_vector_type(4))) float f32x4;
typedef __attribute__((ext_vector_type(4))) unsigned short u16x4;
typedef __attribute__((ext_vector_type(4))) unsigned int u32x4;

__device__ __forceinline__ unsigned short f2bf(float f) {
  unsigned int u = __float_as_uint(f);
  return (unsigned short)((u + 0x7fffu + ((u >> 16) & 1u)) >> 16);  // RNE
}
__device__ __forceinline__ bf16x8 ldb8(const unsigned short* p) {
  return *reinterpret_cast<const bf16x8*>(p);
}

// ---- pack weights to bf16 [M][K] ----
__global__ void pack_weights(const float* __restrict__ wc, const float* __restrict__ wcd,
                             const float* __restrict__ wo, const float* __restrict__ wsk,
                             unsigned short* __restrict__ wpc,   // [256][384] k=tap*128+c
                             unsigned short* __restrict__ wpcd,  // [256][96]  zero-pad k>=80
                             unsigned short* __restrict__ wp2)   // [384][128] rows 0-127 Wout, 128-383 Wskip
{
  int idx = blockIdx.x * 256 + threadIdx.x;
  if (idx < 98304) {
    int o = idx / 384, k = idx - o * 384;
    int tap = k >> 7, c = k & 127;
    wpc[idx] = f2bf(wc[(o * 128 + c) * 3 + tap]);
  } else if (idx < 122880) {
    int i = idx - 98304;
    int o = i / 96, k = i - o * 96;
    wpcd[i] = f2bf(k < CCOND ? wcd[o * CCOND + k] : 0.f);
  } else if (idx < 172032) {
    int i = idx - 122880;
    int m = i >> 7, k = i & 127;
    wp2[i] = f2bf(m < 128 ? wo[m * 128 + k] : wsk[(m - 128) * 128 + k]);
  }
}

// ---- input f32 [B][128][NT] -> bf16 [B][NT][128], paired-u32 stores ----
__global__ void transpose_in64(const float* __restrict__ in, unsigned short* __restrict__ outT)
{
  __shared__ float tile[64][33];
  int t0 = blockIdx.x * 32, c0 = blockIdx.y * 64, b = blockIdx.z;
  int tx = threadIdx.x & 31, ty = threadIdx.x >> 5;  // ty 0..7
  #pragma unroll
  for (int i = 0; i < 8; ++i) {
    int c = c0 + i * 8 + ty;
    tile[i * 8 + ty][tx] = in[((size_t)b * CIN + c) * NT + t0 + tx];
  }
  __syncthreads();
  #pragma unroll
  for (int i = 0; i < 4; ++i) {
    int t = i * 8 + ty;
    unsigned int pk = (unsigned int)f2bf(tile[2 * tx][t]) |
                      ((unsigned int)f2bf(tile[2 * tx + 1][t]) << 16);
    *reinterpret_cast<unsigned int*>(&outT[((size_t)b * NT + t0 + t) * CIN + c0 + 2 * tx]) = pk;
  }
}

// ---- cond f32 [B][80][NT] -> bf16 [B][NT][96] (zero-pad), paired-u32 stores ----
__global__ void transpose_cd(const float* __restrict__ in, unsigned short* __restrict__ outT)
{
  __shared__ float tile[96][33];
  int t0 = blockIdx.x * 32, b = blockIdx.y;
  int tid = threadIdx.x;
  #pragma unroll
  for (int i = 0; i < 12; ++i) {
    int j = i * 256 + tid;
    int c = j >> 5, t = j & 31;
    float v = 0.f;
    if (c < CCOND) v = in[((size_t)b * CCOND + c) * NT + t0 + t];
    tile[c][t] = v;
  }
  __syncthreads();
  #pragma unroll
  for (int i = 0; i < 6; ++i) {
    int j = i * 256 + tid;
    int t = j / 48, cp = j - t * 48;
    unsigned int pk = (unsigned int)f2bf(tile[2 * cp][t]) |
                      ((unsigned int)f2bf(tile[2 * cp + 1][t]) << 16);
    *reinterpret_cast<unsigned int*>(&outT[((size_t)b * NT + t0 + t) * CCP + 2 * cp]) = pk;
  }
}

// ======================= FUSED k1+k2 (v7, 8-wave blocks) =======================
__global__ __launch_bounds__(512, 4) void k12_fused(
    const unsigned short* __restrict__ wpc, const unsigned short* __restrict__ wpcd,
    const unsigned short* __restrict__ wp2, const unsigned short* __restrict__ zp,
    const unsigned short* __restrict__ inT, const unsigned short* __restrict__ cdT,
    const float* __restrict__ bconv, const float* __restrict__ bout,
    const float* __restrict__ bskip, float* __restrict__ out)
{
  __shared__ u32x4 ldsX_[1152];  // 72 rows x 256B, linear; source pre-swizzled
  __shared__ u32x4 ldsC_[768];   // 64 rows x 192B
  __shared__ u32x4 ldsZ_[1024];  // 64 rows x 256B
  char* ldsX = (char*)ldsX_;
  char* ldsC = (char*)ldsC_;
  char* ldsZ = (char*)ldsZ_;

  int b = blockIdx.y;
  int t0 = blockIdx.x * TT;
  int tid = threadIdx.x;
  int lane = tid & 63, w = tid >> 6;            // w 0..7
  int l15 = lane & 15, g = lane >> 4;

  // ---- stage input tile: 1152 granules, pre-swizzled source, linear dest ----
  #pragma unroll
  for (int i = 0; i < 3; ++i) {
    int gi = i * 512 + tid;
    if (gi < 1152) {
      int row = gi >> 4, slot = gi & 15;
      int sg = slot ^ (row & 7);
      int t = t0 - 8 + row;
      const unsigned short* src = (t >= 0)
          ? &inT[((size_t)b * NT + t) * CIN + sg * 8] : zp;
      ldsX_[gi] = *reinterpret_cast<const u32x4*>(src);
    }
  }
  // ---- stage cond tile: 768 granules ----
  #pragma unroll
  for (int i = 0; i < 2; ++i) {
    int gi = i * 512 + tid;
    if (gi < 768) {
      int row = gi / 12, slot = gi - row * 12;
      int sg = slot ^ (row & 3);
      ldsC_[gi] = *reinterpret_cast<const u32x4*>(&cdT[((size_t)b * NT + t0 + row) * CCP + sg * 8]);
    }
  }
  __syncthreads();

  // ---- k1: wave w owns rows 16w..16w+15 (tanh) and 128+16w.. (sigmoid) ----
  int rt = 16 * w + l15, rs = 128 + 16 * w + l15;
  f32x4 at[4] = {}, as_[4] = {};

  #pragma unroll
  for (int grp = 0; grp < 3; ++grp) {
    // batched weight loads for 5 K-steps (10 frags = 40 VGPR in flight)
    bf16x8 wt[5], wss[5];
    #pragma unroll
    for (int q = 0; q < 5; ++q) {
      int s = grp * 5 + q;
      if (s < 12) {
        int tap = s >> 2, kc = s & 3;
        wt[q]  = ldb8(&wpc[(size_t)rt * 384 + tap * 128 + kc * 32 + g * 8]);
        wss[q] = ldb8(&wpc[(size_t)rs * 384 + tap * 128 + kc * 32 + g * 8]);
      } else {
        int kc = s - 12;
        wt[q]  = ldb8(&wpcd[(size_t)rt * CCP + kc * 32 + g * 8]);
        wss[q] = ldb8(&wpcd[(size_t)rs * CCP + kc * 32 + g * 8]);
      }
    }
    #pragma unroll
    for (int q = 0; q < 5; ++q) {
      int s = grp * 5 + q;
      bf16x8 bfr[4];
      if (s < 12) {
        int tap = s >> 2, kc = s & 3;
        int ck = kc * 4 + g;
        #pragma unroll
        for (int nf = 0; nf < 4; ++nf) {
          int tl = nf * 16 + l15 + tap * 4;
          bfr[nf] = *reinterpret_cast<const bf16x8*>(&ldsX[tl * 256 + ((ck ^ (tl & 7)) << 4)]);
        }
      } else {
        int kc = s - 12;
        int ck = kc * 4 + g;
        #pragma unroll
        for (int nf = 0; nf < 4; ++nf) {
          int r = nf * 16 + l15;
          bfr[nf] = *reinterpret_cast<const bf16x8*>(&ldsC[r * 192 + ((ck ^ (r & 3)) << 4)]);
        }
      }
      #pragma unroll
      for (int nf = 0; nf < 4; ++nf) {
        at[nf]  = __builtin_amdgcn_mfma_f32_16x16x32_bf16(wt[q],  bfr[nf], at[nf],  0, 0, 0);
        as_[nf] = __builtin_amdgcn_mfma_f32_16x16x32_bf16(wss[q], bfr[nf], as_[nf], 0, 0, 0);
      }
    }
  }

  float bt[4], bs[4];
  #pragma unroll
  for (int j = 0; j < 4; ++j) {
    bt[j] = bconv[16 * w + g * 4 + j];
    bs[j] = bconv[128 + 16 * w + g * 4 + j];
  }

  // ---- gate in-register -> z into swizzled ldsZ ----
  {
    int cg = 2 * w + (g >> 1);
    int off = (g & 1) * 8;
    #pragma unroll
    for (int nf = 0; nf < 4; ++nf) {
      int tl = nf * 16 + l15;
      u16x4 pk;
      #pragma unroll
      for (int j = 0; j < 4; ++j) {
        float a = at[nf][j] + bt[j];
        float s = as_[nf][j] + bs[j];
        float z = (1.f - 2.f / (1.f + __expf(2.f * a))) * (1.f / (1.f + __expf(-s)));
        pk[j] = f2bf(z);
      }
      *reinterpret_cast<u16x4*>(&ldsZ[tl * 256 + ((cg ^ (tl & 7)) << 4) + off]) = pk;
    }
  }

  // preload k2 weights for kc=0,1 (latency hides under gate/barrier)
  bf16x8 wk2a[3][2];
  #pragma unroll
  for (int mf = 0; mf < 3; ++mf)
    #pragma unroll
    for (int kc = 0; kc < 2; ++kc)
      wk2a[mf][kc] = ldb8(&wp2[(size_t)(48 * w + 16 * mf + l15) * 128 + kc * 32 + g * 8]);

  __syncthreads();

  // ---- k2: [out;skip] rows 48w..48w+47 ----
  f32x4 acc2[3][4] = {};
  #pragma unroll
  for (int kc = 0; kc < 2; ++kc) {
    bf16x8 bfr[4];
    #pragma unroll
    for (int nf = 0; nf < 4; ++nf) {
      int r = nf * 16 + l15;
      bfr[nf] = *reinterpret_cast<const bf16x8*>(&ldsZ[r * 256 + (((kc * 4 + g) ^ (r & 7)) << 4)]);
    }
    #pragma unroll
    for (int mf = 0; mf < 3; ++mf)
      #pragma unroll
      for (int nf = 0; nf < 4; ++nf)
        acc2[mf][nf] = __builtin_amdgcn_mfma_f32_16x16x32_bf16(wk2a[mf][kc], bfr[nf], acc2[mf][nf], 0, 0, 0);
  }
  bf16x8 wk2b[3][2];
  #pragma unroll
  for (int mf = 0; mf < 3; ++mf)
    #pragma unroll
    for (int kc = 0; kc < 2; ++kc)
      wk2b[mf][kc] = ldb8(&wp2[(size_t)(48 * w + 16 * mf + l15) * 128 + (kc + 2) * 32 + g * 8]);
  #pragma unroll
  for (int kc = 2; kc < 4; ++kc) {
    bf16x8 bfr[4];
    #pragma unroll
    for (int nf = 0; nf < 4; ++nf) {
      int r = nf * 16 + l15;
      bfr[nf] = *reinterpret_cast<const bf16x8*>(&ldsZ[r * 256 + (((kc * 4 + g) ^ (r & 7)) << 4)]);
    }
    #pragma unroll
    for (int mf = 0; mf < 3; ++mf)
      #pragma unroll
      for (int nf = 0; nf < 4; ++nf)
        acc2[mf][nf] = __builtin_amdgcn_mfma_f32_16x16x32_bf16(wk2b[mf][kc - 2], bfr[nf], acc2[mf][nf], 0, 0, 0);
  }

  float* skipp = out + (size_t)NB * 128 * NT;
  #pragma unroll
  for (int mf = 0; mf < 3; ++mf) {
    int mrow = 48 * w + 16 * mf + g * 4;
    #pragma unroll
    for (int j = 0; j < 4; ++j) {
      int m = mrow + j;
      float bv;
      float* basep;
      if (m < 128) { bv = bout[m];        basep = out   + ((size_t)b * 128 + m) * NT; }
      else         { bv = bskip[m - 128]; basep = skipp + ((size_t)b * 256 + (m - 128)) * NT; }
      #pragma unroll
      for (int nf = 0; nf < 4; ++nf)
        basep[t0 + nf * 16 + l15] = acc2[mf][nf][j] + bv;
    }
  }
}

extern "C" void kernel_launch(void* const* d_in, const int* in_sizes, int n_in,
                              void* d_out, int out_size, void* d_ws, size_t ws_size,
                              hipStream_t stream)
{
  const float* input = (const float*)d_in[0];
  const float* cond  = (const float*)d_in[1];
  const float* wconv = (const float*)d_in[2];
  const float* bconv = (const float*)d_in[3];
  const float* wcond = (const float*)d_in[4];
  const float* wout  = (const float*)d_in[5];
  const float* boutp = (const float*)d_in[6];
  const float* wskip = (const float*)d_in[7];
  const float* bskip = (const float*)d_in[8];
  float* out = (float*)d_out;

  unsigned short* wpc  = (unsigned short*)d_ws;     //  98304
  unsigned short* wpcd = wpc + 98304;               //  24576 (elems 80..95 of each row are zero)
  unsigned short* wp2  = wpcd + 24576;              //  49152
  unsigned short* inT  = wp2 + 49152;               //  16,384,000 elems
  unsigned short* cdT  = inT + (size_t)16384000;    //  12,288,000 elems
  const unsigned short* zp = wpcd + 80;             //  16B of guaranteed zeros (pad region)

  pack_weights<<<672, 256, 0, stream>>>(wconv, wcond, wout, wskip, wpc, wpcd, wp2);
  transpose_in64<<<dim3(500, 2, NB), 256, 0, stream>>>(input, inT);
  transpose_cd<<<dim3(500, NB), 256, 0, stream>>>(cond, cdT);
  k12_fused<<<dim3(250, NB), 512, 0, stream>>>(wpc, wpcd, wp2, zp, inT, cdT,
                                               bconv, boutp, bskip, out);
}

// Round 8
// 143.339 us; speedup vs baseline: 1.3903x; 1.0483x over previous
//
#include <hip/hip_runtime.h>

// WaveNet gated residual block, MI355X bf16-MFMA implementation (v8).
// v8 changes vs v7 (113us k12, VGPR=52 proving weight-load batching was
// re-sunk by the compiler; occupancy 39% from 47KB LDS):
//  1) LDS union: cond tile and z tile share one buffer (cond dead after k1)
//     -> 34.8KB LDS -> 4 blocks/CU (occupancy cap 100%).
//  2) Weight loads batched in groups of 3 K-steps (6 frags = 48 VGPR) and
//     PINNED with __builtin_amdgcn_sched_barrier(0) between the load batch
//     and the MFMA cluster so the scheduler cannot sink them back to
//     just-in-time. Same for k2's weight halves.
//  3) Staging via __builtin_amdgcn_global_load_lds (16B): dest is linear in
//     lane (wave-uniform base + lane*16), source pre-swizzled per-lane.
//  4) transposes merged into one launch.

#define NB 8
#define NT 16000
#define CIN 128
#define CCOND 80
#define CCP 96
#define TT 64

typedef __attribute__((ext_vector_type(8))) __bf16 bf16x8;
typedef __attribute__((ext_vector_type(4))) float f32x4;
typedef __attribute__((ext_vector_type(4))) unsigned short u16x4;
typedef __attribute__((ext_vector_type(4))) unsigned int u32x4;

__device__ __forceinline__ unsigned short f2bf(float f) {
  unsigned int u = __float_as_uint(f);
  return (unsigned short)((u + 0x7fffu + ((u >> 16) & 1u)) >> 16);  // RNE
}
__device__ __forceinline__ bf16x8 ldb8(const unsigned short* p) {
  return *reinterpret_cast<const bf16x8*>(p);
}
__device__ __forceinline__ void gl_lds16(const unsigned short* g, void* l) {
  __builtin_amdgcn_global_load_lds(
      (const __attribute__((address_space(1))) unsigned int*)g,
      (__attribute__((address_space(3))) unsigned int*)l, 16, 0, 0);
}

// ---- pack weights to bf16 [M][K] ----
__global__ void pack_weights(const float* __restrict__ wc, const float* __restrict__ wcd,
                             const float* __restrict__ wo, const float* __restrict__ wsk,
                             unsigned short* __restrict__ wpc,   // [256][384] k=tap*128+c
                             unsigned short* __restrict__ wpcd,  // [256][96]  zero-pad k>=80
                             unsigned short* __restrict__ wp2)   // [384][128] rows 0-127 Wout, 128-383 Wskip
{
  int idx = blockIdx.x * 256 + threadIdx.x;
  if (idx < 98304) {
    int o = idx / 384, k = idx - o * 384;
    int tap = k >> 7, c = k & 127;
    wpc[idx] = f2bf(wc[(o * 128 + c) * 3 + tap]);
  } else if (idx < 122880) {
    int i = idx - 98304;
    int o = i / 96, k = i - o * 96;
    wpcd[i] = f2bf(k < CCOND ? wcd[o * CCOND + k] : 0.f);
  } else if (idx < 172032) {
    int i = idx - 122880;
    int m = i >> 7, k = i & 127;
    wp2[i] = f2bf(m < 128 ? wo[m * 128 + k] : wsk[(m - 128) * 128 + k]);
  }
}

// ---- merged transpose: y<2 -> input halves, y==2 -> cond ----
__global__ void transpose_prep(const float* __restrict__ in, const float* __restrict__ cond,
                               unsigned short* __restrict__ inT, unsigned short* __restrict__ cdT)
{
  __shared__ float tile[96][33];
  int b = blockIdx.z;
  int t0 = blockIdx.x * 32;
  if (blockIdx.y < 2) {
    int c0 = blockIdx.y * 64;
    int tx = threadIdx.x & 31, ty = threadIdx.x >> 5;  // ty 0..7
    #pragma unroll
    for (int i = 0; i < 8; ++i) {
      int c = c0 + i * 8 + ty;
      tile[i * 8 + ty][tx] = in[((size_t)b * CIN + c) * NT + t0 + tx];
    }
    __syncthreads();
    #pragma unroll
    for (int i = 0; i < 4; ++i) {
      int t = i * 8 + ty;
      unsigned int pk = (unsigned int)f2bf(tile[2 * tx][t]) |
                        ((unsigned int)f2bf(tile[2 * tx + 1][t]) << 16);
      *reinterpret_cast<unsigned int*>(&inT[((size_t)b * NT + t0 + t) * CIN + c0 + 2 * tx]) = pk;
    }
  } else {
    int tid = threadIdx.x;
    #pragma unroll
    for (int i = 0; i < 12; ++i) {
      int j = i * 256 + tid;
      int c = j >> 5, t = j & 31;
      float v = 0.f;
      if (c < CCOND) v = cond[((size_t)b * CCOND + c) * NT + t0 + t];
      tile[c][t] = v;
    }
    __syncthreads();
    #pragma unroll
    for (int i = 0; i < 6; ++i) {
      int j = i * 256 + tid;
      int t = j / 48, cp = j - t * 48;
      unsigned int pk = (unsigned int)f2bf(tile[2 * cp][t]) |
                        ((unsigned int)f2bf(tile[2 * cp + 1][t]) << 16);
      *reinterpret_cast<unsigned int*>(&cdT[((size_t)b * NT + t0 + t) * CCP + 2 * cp]) = pk;
    }
  }
}

// ======================= FUSED k1+k2 (v8) =======================
__global__ __launch_bounds__(512, 4) void k12_fused(
    const unsigned short* __restrict__ wpc, const unsigned short* __restrict__ wpcd,
    const unsigned short* __restrict__ wp2, const unsigned short* __restrict__ zp,
    const unsigned short* __restrict__ inT, const unsigned short* __restrict__ cdT,
    const float* __restrict__ bconv, const float* __restrict__ bout,
    const float* __restrict__ bskip, float* __restrict__ out)
{
  __shared__ u32x4 ldsX_[1152];  // 72 rows x 256B, linear dest; source pre-swizzled
  __shared__ u32x4 ldsU_[1024];  // UNION: cond [64 x 192B] (phase 1) / z [64 x 256B] (phase 2)
  char* ldsX = (char*)ldsX_;
  char* ldsU = (char*)ldsU_;

  int b = blockIdx.y;
  int t0 = blockIdx.x * TT;
  int tid = threadIdx.x;
  int lane = tid & 63, w = tid >> 6;            // w 0..7
  int l15 = lane & 15, g = lane >> 4;

  // ---- stage input tile: 1152 granules via global_load_lds ----
  #pragma unroll
  for (int i = 0; i < 3; ++i) {
    int gbase = i * 512 + 64 * w;               // wave-uniform
    if (gbase < 1152) {
      int gi = gbase + lane;
      int row = gi >> 4, slot = gi & 15;
      int sg = slot ^ (row & 7);
      int t = t0 - 8 + row;
      const unsigned short* src = (t >= 0)
          ? &inT[((size_t)b * NT + t) * CIN + sg * 8] : zp;
      gl_lds16(src, ldsX + gbase * 16);
    }
  }
  // ---- stage cond tile: 768 granules into ldsU ----
  #pragma unroll
  for (int i = 0; i < 2; ++i) {
    int gbase = i * 512 + 64 * w;
    if (gbase < 768) {
      int gi = gbase + lane;
      int row = gi / 12, slot = gi - row * 12;
      int sg = slot ^ (row & 3);
      gl_lds16(&cdT[((size_t)b * NT + t0 + row) * CCP + sg * 8], ldsU + gbase * 16);
    }
  }
  __syncthreads();

  // ---- k1: wave w owns rows 16w..16w+15 (tanh) and 128+16w.. (sigmoid) ----
  int rt = 16 * w + l15, rs = 128 + 16 * w + l15;
  f32x4 at[4] = {}, as_[4] = {};

  #pragma unroll
  for (int gg = 0; gg < 5; ++gg) {
    // batched weight loads for 3 K-steps (6 frags = 48 VGPR), pinned
    bf16x8 wt[3], wss[3];
    #pragma unroll
    for (int q = 0; q < 3; ++q) {
      int s = gg * 3 + q;
      if (s < 12) {
        int tap = s >> 2, kc = s & 3;
        wt[q]  = ldb8(&wpc[(size_t)rt * 384 + tap * 128 + kc * 32 + g * 8]);
        wss[q] = ldb8(&wpc[(size_t)rs * 384 + tap * 128 + kc * 32 + g * 8]);
      } else {
        int kc = s - 12;
        wt[q]  = ldb8(&wpcd[(size_t)rt * CCP + kc * 32 + g * 8]);
        wss[q] = ldb8(&wpcd[(size_t)rs * CCP + kc * 32 + g * 8]);
      }
    }
    __builtin_amdgcn_sched_barrier(0);   // do NOT sink the loads into the MFMA loop
    #pragma unroll
    for (int q = 0; q < 3; ++q) {
      int s = gg * 3 + q;
      bf16x8 bfr[4];
      if (s < 12) {
        int tap = s >> 2, kc = s & 3;
        int ck = kc * 4 + g;
        #pragma unroll
        for (int nf = 0; nf < 4; ++nf) {
          int tl = nf * 16 + l15 + tap * 4;
          bfr[nf] = *reinterpret_cast<const bf16x8*>(&ldsX[tl * 256 + ((ck ^ (tl & 7)) << 4)]);
        }
      } else {
        int kc = s - 12;
        int ck = kc * 4 + g;
        #pragma unroll
        for (int nf = 0; nf < 4; ++nf) {
          int r = nf * 16 + l15;
          bfr[nf] = *reinterpret_cast<const bf16x8*>(&ldsU[r * 192 + ((ck ^ (r & 3)) << 4)]);
        }
      }
      #pragma unroll
      for (int nf = 0; nf < 4; ++nf) {
        at[nf]  = __builtin_amdgcn_mfma_f32_16x16x32_bf16(wt[q],  bfr[nf], at[nf],  0, 0, 0);
        as_[nf] = __builtin_amdgcn_mfma_f32_16x16x32_bf16(wss[q], bfr[nf], as_[nf], 0, 0, 0);
      }
    }
  }

  float bt[4], bs[4];
  #pragma unroll
  for (int j = 0; j < 4; ++j) {
    bt[j] = bconv[16 * w + g * 4 + j];
    bs[j] = bconv[128 + 16 * w + g * 4 + j];
  }

  // preload k2 weights kc=0,1 (latency hides under barrier+gate)
  bf16x8 wk2a[3][2];
  #pragma unroll
  for (int mf = 0; mf < 3; ++mf)
    #pragma unroll
    for (int kc = 0; kc < 2; ++kc)
      wk2a[mf][kc] = ldb8(&wp2[(size_t)(48 * w + 16 * mf + l15) * 128 + kc * 32 + g * 8]);

  __syncthreads();   // all waves done reading cond region; ldsU becomes z

  // ---- gate in-register -> z into swizzled ldsU [64 rows][256B] ----
  {
    int cg = 2 * w + (g >> 1);
    int off = (g & 1) * 8;
    #pragma unroll
    for (int nf = 0; nf < 4; ++nf) {
      int tl = nf * 16 + l15;
      u16x4 pk;
      #pragma unroll
      for (int j = 0; j < 4; ++j) {
        float a = at[nf][j] + bt[j];
        float s = as_[nf][j] + bs[j];
        float z = (1.f - 2.f / (1.f + __expf(2.f * a))) * (1.f / (1.f + __expf(-s)));
        pk[j] = f2bf(z);
      }
      *reinterpret_cast<u16x4*>(&ldsU[tl * 256 + ((cg ^ (tl & 7)) << 4) + off]) = pk;
    }
  }
  __syncthreads();

  // ---- k2: [out;skip] rows 48w..48w+47 ----
  f32x4 acc2[3][4] = {};
  #pragma unroll
  for (int kc = 0; kc < 2; ++kc) {
    bf16x8 bfr[4];
    #pragma unroll
    for (int nf = 0; nf < 4; ++nf) {
      int r = nf * 16 + l15;
      bfr[nf] = *reinterpret_cast<const bf16x8*>(&ldsU[r * 256 + (((kc * 4 + g) ^ (r & 7)) << 4)]);
    }
    #pragma unroll
    for (int mf = 0; mf < 3; ++mf)
      #pragma unroll
      for (int nf = 0; nf < 4; ++nf)
        acc2[mf][nf] = __builtin_amdgcn_mfma_f32_16x16x32_bf16(wk2a[mf][kc], bfr[nf], acc2[mf][nf], 0, 0, 0);
  }
  bf16x8 wk2b[3][2];
  #pragma unroll
  for (int mf = 0; mf < 3; ++mf)
    #pragma unroll
    for (int kc = 0; kc < 2; ++kc)
      wk2b[mf][kc] = ldb8(&wp2[(size_t)(48 * w + 16 * mf + l15) * 128 + (kc + 2) * 32 + g * 8]);
  __builtin_amdgcn_sched_barrier(0);
  #pragma unroll
  for (int kc = 2; kc < 4; ++kc) {
    bf16x8 bfr[4];
    #pragma unroll
    for (int nf = 0; nf < 4; ++nf) {
      int r = nf * 16 + l15;
      bfr[nf] = *reinterpret_cast<const bf16x8*>(&ldsU[r * 256 + (((kc * 4 + g) ^ (r & 7)) << 4)]);
    }
    #pragma unroll
    for (int mf = 0; mf < 3; ++mf)
      #pragma unroll
      for (int nf = 0; nf < 4; ++nf)
        acc2[mf][nf] = __builtin_amdgcn_mfma_f32_16x16x32_bf16(wk2b[mf][kc - 2], bfr[nf], acc2[mf][nf], 0, 0, 0);
  }

  float* skipp = out + (size_t)NB * 128 * NT;
  #pragma unroll
  for (int mf = 0; mf < 3; ++mf) {
    int mrow = 48 * w + 16 * mf + g * 4;
    #pragma unroll
    for (int j = 0; j < 4; ++j) {
      int m = mrow + j;
      float bv;
      float* basep;
      if (m < 128) { bv = bout[m];        basep = out   + ((size_t)b * 128 + m) * NT; }
      else         { bv = bskip[m - 128]; basep = skipp + ((size_t)b * 256 + (m - 128)) * NT; }
      #pragma unroll
      for (int nf = 0; nf < 4; ++nf)
        basep[t0 + nf * 16 + l15] = acc2[mf][nf][j] + bv;
    }
  }
}

extern "C" void kernel_launch(void* const* d_in, const int* in_sizes, int n_in,
                              void* d_out, int out_size, void* d_ws, size_t ws_size,
                              hipStream_t stream)
{
  const float* input = (const float*)d_in[0];
  const float* cond  = (const float*)d_in[1];
  const float* wconv = (const float*)d_in[2];
  const float* bconv = (const float*)d_in[3];
  const float* wcond = (const float*)d_in[4];
  const float* wout  = (const float*)d_in[5];
  const float* boutp = (const float*)d_in[6];
  const float* wskip = (const float*)d_in[7];
  const float* bskip = (const float*)d_in[8];
  float* out = (float*)d_out;

  unsigned short* wpc  = (unsigned short*)d_ws;     //  98304
  unsigned short* wpcd = wpc + 98304;               //  24576 (elems 80..95 of each row are zero)
  unsigned short* wp2  = wpcd + 24576;              //  49152
  unsigned short* inT  = wp2 + 49152;               //  16,384,000 elems
  unsigned short* cdT  = inT + (size_t)16384000;    //  12,288,000 elems
  const unsigned short* zp = wpcd + 80;             //  16B of guaranteed zeros (pad region)

  pack_weights<<<672, 256, 0, stream>>>(wconv, wcond, wout, wskip, wpc, wpcd, wp2);
  transpose_prep<<<dim3(500, 3, NB), 256, 0, stream>>>(input, cond, inT, cdT);
  k12_fused<<<dim3(250, NB), 512, 0, stream>>>(wpc, wpcd, wp2, zp, inT, cdT,
                                               bconv, boutp, bskip, out);
}

// Round 9
// 131.345 us; speedup vs baseline: 1.5173x; 1.0913x over previous
//
#include <hip/hip_runtime.h>

// WaveNet gated residual block, MI355X bf16-MFMA implementation (v9).
// v9: transpose pre-pass FUSED into k12. Staging reads raw f32 [B][C][T]
// directly with transpose-pattern coalesced scalar loads (64 lanes = 64
// consecutive t = 256B segments), converts to bf16 in-register, ds_writes the
// swizzled LDS tile. Deletes the transpose kernel (~30us) and its 114MB HBM
// round-trip. k2 restructured per-mf: compute 16 rows -> store immediately,
// prefetch next mf's weights under the stores (de-bursts the epilogue,
// acc2 48->16 live VGPR). Everything else = v8 (110us k12, VGPR=56).

#define NB 8
#define NT 16000
#define CIN 128
#define CCOND 80
#define CCP 96
#define TT 64

typedef __attribute__((ext_vector_type(8))) __bf16 bf16x8;
typedef __attribute__((ext_vector_type(4))) float f32x4;
typedef __attribute__((ext_vector_type(4))) unsigned short u16x4;
typedef __attribute__((ext_vector_type(4))) unsigned int u32x4;

__device__ __forceinline__ unsigned short f2bf(float f) {
  unsigned int u = __float_as_uint(f);
  return (unsigned short)((u + 0x7fffu + ((u >> 16) & 1u)) >> 16);  // RNE
}
__device__ __forceinline__ bf16x8 ldb8(const unsigned short* p) {
  return *reinterpret_cast<const bf16x8*>(p);
}

// ---- pack weights to bf16 [M][K] ----
__global__ void pack_weights(const float* __restrict__ wc, const float* __restrict__ wcd,
                             const float* __restrict__ wo, const float* __restrict__ wsk,
                             unsigned short* __restrict__ wpc,   // [256][384] k=tap*128+c
                             unsigned short* __restrict__ wpcd,  // [256][96]  zero-pad k>=80
                             unsigned short* __restrict__ wp2)   // [384][128] rows 0-127 Wout, 128-383 Wskip
{
  int idx = blockIdx.x * 256 + threadIdx.x;
  if (idx < 98304) {
    int o = idx / 384, k = idx - o * 384;
    int tap = k >> 7, c = k & 127;
    wpc[idx] = f2bf(wc[(o * 128 + c) * 3 + tap]);
  } else if (idx < 122880) {
    int i = idx - 98304;
    int o = i / 96, k = i - o * 96;
    wpcd[i] = f2bf(k < CCOND ? wcd[o * CCOND + k] : 0.f);
  } else if (idx < 172032) {
    int i = idx - 122880;
    int m = i >> 7, k = i & 127;
    wp2[i] = f2bf(m < 128 ? wo[m * 128 + k] : wsk[(m - 128) * 128 + k]);
  }
}

// ======================= FUSED transpose+k1+k2 (v9) =======================
__global__ __launch_bounds__(512, 4) void k12_fused(
    const unsigned short* __restrict__ wpc, const unsigned short* __restrict__ wpcd,
    const unsigned short* __restrict__ wp2,
    const float* __restrict__ in, const float* __restrict__ cond,
    const float* __restrict__ bconv, const float* __restrict__ bout,
    const float* __restrict__ bskip, float* __restrict__ out)
{
  __shared__ u32x4 ldsX_[1152];  // X tile [72 t-rows][16 ch-granules x 16B], swizzled
  __shared__ u32x4 ldsU_[1024];  // UNION: cond [64][12x16B] / z [64][16x16B], swizzled
  char* ldsX = (char*)ldsX_;
  char* ldsU = (char*)ldsU_;

  int b = blockIdx.y;
  int t0 = blockIdx.x * TT;
  int tid = threadIdx.x;
  int lane = tid & 63, w = tid >> 6;            // w 0..7
  int l15 = lane & 15, g = lane >> 4;

  // ---- stage X from raw f32: task gi = gch*72 + row (lanes = consecutive t) ----
  #pragma unroll
  for (int rep = 0; rep < 3; ++rep) {
    int gi = rep * 512 + tid;
    if (gi < 1152) {
      int gch = gi / 72;                        // channel granule 0..15
      int row = gi - gch * 72;                  // t-local 0..71
      int t = t0 - 8 + row;
      u32x4 pk = {};
      if (t >= 0) {
        const float* src = &in[((size_t)b * CIN + gch * 8) * NT + t];
        #pragma unroll
        for (int p = 0; p < 4; ++p) {
          float v0 = src[(size_t)(2 * p) * NT];
          float v1 = src[(size_t)(2 * p + 1) * NT];
          pk[p] = (unsigned)f2bf(v0) | ((unsigned)f2bf(v1) << 16);
        }
      }
      *reinterpret_cast<u32x4*>(&ldsX[row * 256 + ((gch ^ (row & 7)) << 4)]) = pk;
    }
  }
  // ---- stage cond from raw f32: task gi = gch*64 + row; granules 10,11 = pad ----
  #pragma unroll
  for (int rep = 0; rep < 2; ++rep) {
    int gi = rep * 512 + tid;
    if (gi < 768) {
      int gch = gi >> 6;                        // 0..11
      int row = gi & 63;
      u32x4 pk = {};
      if (gch < 10) {
        const float* src = &cond[((size_t)b * CCOND + gch * 8) * NT + t0 + row];
        #pragma unroll
        for (int p = 0; p < 4; ++p) {
          float v0 = src[(size_t)(2 * p) * NT];
          float v1 = src[(size_t)(2 * p + 1) * NT];
          pk[p] = (unsigned)f2bf(v0) | ((unsigned)f2bf(v1) << 16);
        }
      }
      *reinterpret_cast<u32x4*>(&ldsU[row * 192 + ((gch ^ (row & 3)) << 4)]) = pk;
    }
  }
  __syncthreads();

  // ---- k1: wave w owns rows 16w..16w+15 (tanh) and 128+16w.. (sigmoid) ----
  int rt = 16 * w + l15, rs = 128 + 16 * w + l15;
  f32x4 at[4] = {}, as_[4] = {};

  #pragma unroll
  for (int gg = 0; gg < 5; ++gg) {
    // batched weight loads for 3 K-steps (6 frags = 24 VGPR), pinned
    bf16x8 wt[3], wss[3];
    #pragma unroll
    for (int q = 0; q < 3; ++q) {
      int s = gg * 3 + q;
      if (s < 12) {
        int tap = s >> 2, kc = s & 3;
        wt[q]  = ldb8(&wpc[(size_t)rt * 384 + tap * 128 + kc * 32 + g * 8]);
        wss[q] = ldb8(&wpc[(size_t)rs * 384 + tap * 128 + kc * 32 + g * 8]);
      } else {
        int kc = s - 12;
        wt[q]  = ldb8(&wpcd[(size_t)rt * CCP + kc * 32 + g * 8]);
        wss[q] = ldb8(&wpcd[(size_t)rs * CCP + kc * 32 + g * 8]);
      }
    }
    __builtin_amdgcn_sched_barrier(0);   // keep the load batch ahead of the MFMAs
    #pragma unroll
    for (int q = 0; q < 3; ++q) {
      int s = gg * 3 + q;
      bf16x8 bfr[4];
      if (s < 12) {
        int tap = s >> 2, kc = s & 3;
        int ck = kc * 4 + g;
        #pragma unroll
        for (int nf = 0; nf < 4; ++nf) {
          int tl = nf * 16 + l15 + tap * 4;
          bfr[nf] = *reinterpret_cast<const bf16x8*>(&ldsX[tl * 256 + ((ck ^ (tl & 7)) << 4)]);
        }
      } else {
        int kc = s - 12;
        int ck = kc * 4 + g;
        #pragma unroll
        for (int nf = 0; nf < 4; ++nf) {
          int r = nf * 16 + l15;
          bfr[nf] = *reinterpret_cast<const bf16x8*>(&ldsU[r * 192 + ((ck ^ (r & 3)) << 4)]);
        }
      }
      #pragma unroll
      for (int nf = 0; nf < 4; ++nf) {
        at[nf]  = __builtin_amdgcn_mfma_f32_16x16x32_bf16(wt[q],  bfr[nf], at[nf],  0, 0, 0);
        as_[nf] = __builtin_amdgcn_mfma_f32_16x16x32_bf16(wss[q], bfr[nf], as_[nf], 0, 0, 0);
      }
    }
  }

  float bt[4], bs[4];
  #pragma unroll
  for (int j = 0; j < 4; ++j) {
    bt[j] = bconv[16 * w + g * 4 + j];
    bs[j] = bconv[128 + 16 * w + g * 4 + j];
  }

  // preload k2 weights for mf=0 (latency hides under barrier+gate)
  bf16x8 wk2buf[2][4];
  #pragma unroll
  for (int kc = 0; kc < 4; ++kc)
    wk2buf[0][kc] = ldb8(&wp2[(size_t)(48 * w + l15) * 128 + kc * 32 + g * 8]);

  __syncthreads();   // all waves done reading cond region; ldsU becomes z

  // ---- gate in-register -> z into swizzled ldsU [64 rows][256B] ----
  {
    int cg = 2 * w + (g >> 1);
    int off = (g & 1) * 8;
    #pragma unroll
    for (int nf = 0; nf < 4; ++nf) {
      int tl = nf * 16 + l15;
      u16x4 pk;
      #pragma unroll
      for (int j = 0; j < 4; ++j) {
        float a = at[nf][j] + bt[j];
        float s = as_[nf][j] + bs[j];
        float z = (1.f - 2.f / (1.f + __expf(2.f * a))) * (1.f / (1.f + __expf(-s)));
        pk[j] = f2bf(z);
      }
      *reinterpret_cast<u16x4*>(&ldsU[tl * 256 + ((cg ^ (tl & 7)) << 4) + off]) = pk;
    }
  }
  __syncthreads();

  // ---- k2 per-mf: compute 16 rows, store immediately; prefetch next mf ----
  float* skipp = out + (size_t)NB * 128 * NT;
  #pragma unroll
  for (int mf = 0; mf < 3; ++mf) {
    bf16x8* wcur = wk2buf[mf & 1];
    bf16x8* wnx  = wk2buf[(mf + 1) & 1];
    if (mf < 2) {
      #pragma unroll
      for (int kc = 0; kc < 4; ++kc)
        wnx[kc] = ldb8(&wp2[(size_t)(48 * w + 16 * (mf + 1) + l15) * 128 + kc * 32 + g * 8]);
    }
    __builtin_amdgcn_sched_barrier(0);
    f32x4 am[4] = {};
    #pragma unroll
    for (int kc = 0; kc < 4; ++kc) {
      bf16x8 bfr[4];
      #pragma unroll
      for (int nf = 0; nf < 4; ++nf) {
        int r = nf * 16 + l15;
        bfr[nf] = *reinterpret_cast<const bf16x8*>(&ldsU[r * 256 + (((kc * 4 + g) ^ (r & 7)) << 4)]);
      }
      #pragma unroll
      for (int nf = 0; nf < 4; ++nf)
        am[nf] = __builtin_amdgcn_mfma_f32_16x16x32_bf16(wcur[kc], bfr[nf], am[nf], 0, 0, 0);
    }
    int mrow = 48 * w + 16 * mf + g * 4;
    #pragma unroll
    for (int j = 0; j < 4; ++j) {
      int m = mrow + j;
      float bv;
      float* basep;
      if (m < 128) { bv = bout[m];        basep = out   + ((size_t)b * 128 + m) * NT; }
      else         { bv = bskip[m - 128]; basep = skipp + ((size_t)b * 256 + (m - 128)) * NT; }
      #pragma unroll
      for (int nf = 0; nf < 4; ++nf)
        basep[t0 + nf * 16 + l15] = am[nf][j] + bv;
    }
  }
}

extern "C" void kernel_launch(void* const* d_in, const int* in_sizes, int n_in,
                              void* d_out, int out_size, void* d_ws, size_t ws_size,
                              hipStream_t stream)
{
  const float* input = (const float*)d_in[0];
  const float* cond  = (const float*)d_in[1];
  const float* wconv = (const float*)d_in[2];
  const float* bconv = (const float*)d_in[3];
  const float* wcond = (const float*)d_in[4];
  const float* wout  = (const float*)d_in[5];
  const float* boutp = (const float*)d_in[6];
  const float* wskip = (const float*)d_in[7];
  const float* bskip = (const float*)d_in[8];
  float* out = (float*)d_out;

  unsigned short* wpc  = (unsigned short*)d_ws;     //  98304 elems
  unsigned short* wpcd = wpc + 98304;               //  24576 elems
  unsigned short* wp2  = wpcd + 24576;              //  49152 elems

  pack_weights<<<672, 256, 0, stream>>>(wconv, wcond, wout, wskip, wpc, wpcd, wp2);
  k12_fused<<<dim3(250, NB), 512, 0, stream>>>(wpc, wpcd, wp2, input, cond,
                                               bconv, boutp, bskip, out);
}